// Round 11
// baseline (175.007 us; speedup 1.0000x reference)
//
#include <hip/hip_runtime.h>
#include <hip/hip_bf16.h>

#define C1_CONST 4.7e-9f
#define CHUNK 4       // output steps per chunk (3750 waves -> ~3.7 waves/SIMD)
#define WARM  12      // warm-up steps; |rho|~0.5 measured -> init err ~1e-4 << f16 floor
#define CPW   32      // chunks per wave (MFMA batch)

typedef _Float16 f16;
typedef unsigned int u32;
typedef f16   f16x8  __attribute__((ext_vector_type(8)));
typedef u32   u32x4  __attribute__((ext_vector_type(4)));
typedef float f32x16 __attribute__((ext_vector_type(16)));

#define MFMA(A, B, C) __builtin_amdgcn_mfma_f32_32x32x16_f16((A), (B), (C), 0, 0, 0)

// Pack two f32 -> packed f16 pair (single v_cvt_pkrtz).
__device__ __forceinline__ u32 packp(float x0, float x1) {
    return __builtin_bit_cast(u32, __builtin_amdgcn_cvt_pkrtz(x0, x1));
}

// Single kernel: 32 chunks per wave, hidden layers via v_mfma_f32_32x32x16_f16,
// pure f16 operands (validated r9/r10: absmax 1.95e-3 vs 1.375e-2 threshold).
// Per-step WDF port scalars computed INLINE (approx v_rcp, rel err ~1e-7).
//
// LOGICAL-K REMAP (exact): k = (jj&3) + 4*h + 8*(jj>>2) + 16*s, so half h's
// B k-set equals the C/D rows it owns (row=(reg&3)+8*(reg>>2)+4*h) and
// D reg r = jj + 8*s: B0 = relu(D[0..7]), B1 = relu(D[8..15]) with zero
// cross-lane exchange between layers.
//
// Uses the P0 == 1 identity (g0 = g1+g2 exactly), so the a0 carry vanishes:
//   dp_a = P1*b1 + P2*v,  b1' = dp_a + dp_b - b1,  out = 0.5*(dp_a+dp_b)
__global__ __launch_bounds__(64, 4) void scan_kernel(
    const float* __restrict__ v_in, const float* __restrict__ vs_r,
    const float* __restrict__ fs,
    const float* __restrict__ W_in, const float* __restrict__ b_in,
    const float* __restrict__ W_h,  const float* __restrict__ b_h,
    const float* __restrict__ W_out, const float* __restrict__ b_out,
    float* __restrict__ out, int T) {
    const int lane = threadIdx.x & 63;
    const int c    = lane & 31;   // chunk slot / MFMA col / weight row m
    const int h    = lane >> 5;
    const int xaddr = (lane ^ 32) << 2;   // ds_bpermute addr for xor-32

    auto xr32 = [&](float v) {
        return __int_as_float(__builtin_amdgcn_ds_bpermute(xaddr, __float_as_int(v)));
    };

    // ---- MFMA A fragments (f16) for the two hidden layers ----
    f16x8 AA0, AA1, AB0, AB1;
#pragma unroll
    for (int jj = 0; jj < 8; ++jj) {
        int k0 = (jj & 3) + 4 * h + 8 * (jj >> 2);   // s=0
        int k1 = k0 + 16;                            // s=1
        AA0[jj] = (f16)W_h[c * 32 + k0];
        AA1[jj] = (f16)W_h[c * 32 + k1];
        AB0[jj] = (f16)W_h[1024 + c * 32 + k0];
        AB1[jj] = (f16)W_h[1024 + c * 32 + k1];
    }

    // ---- biases in C/D layout; W_out by C/D row ----
    f32x16 bAf, bBf;
    float wo_r[16];
#pragma unroll
    for (int r = 0; r < 16; ++r) {
        int row = (r & 3) + 8 * (r >> 2) + 4 * h;
        bAf[r] = b_h[row];
        bBf[r] = b_h[32 + row];
        wo_r[r] = W_out[row];
    }
    const float bo = b_out[0];

    // ---- input-layer constants, in B-slot order u = s*8 + jj ----
    float wi0c[16], wi1c[16], bic[16];
#pragma unroll
    for (int s = 0; s < 2; ++s)
#pragma unroll
        for (int jj = 0; jj < 8; ++jj) {
            int k = (jj & 3) + 4 * h + 8 * (jj >> 2) + 16 * s;
            wi0c[s * 8 + jj] = W_in[2 * k];
            wi1c[s * 8 + jj] = W_in[2 * k + 1];
            bic[s * 8 + jj]  = b_in[k];
        }

    const int cg = blockIdx.x * CPW + c;   // global chunk id
    const int ts = cg * CHUNK;             // first output step of this chunk

    // Inline per-step scalars: g1 = 2*C1*fs, g2 ~= 1/vs_r, inv ~= 1/(g1+g2);
    // P1 = g1*inv, pv = g2*inv*v, dr = inv/3000   (r0 = 1/(g1+g2) exactly).
    auto load_pre = [&](int tt, float& P1, float& pv, float& dr) {
        int tc = min(max(tt, 0), T - 1);
        float f  = fs[tc];
        float vr = vs_r[tc];
        float vv = v_in[tc];
        float g1 = (2.0f * C1_CONST) * f;
        float g2 = __builtin_amdgcn_rcpf(vr);
        float inv = __builtin_amdgcn_rcpf(g1 + g2);
        P1 = g1 * inv;
        pv = g2 * inv * vv;
        dr = inv * (1.0f / 3000.0f);
    };

    float b1 = 0.0f;
    float P1, pv, dr;
    load_pre(ts - WARM, P1, pv, dr);

    for (int j = -WARM; j < CHUNK; ++j) {
        const int t = ts + j;
        // prefetch next step's scalars (independent of this step's compute)
        float nP1, npv, ndr;
        load_pre(t + 1, nP1, npv, ndr);

        // dp_a = P1*b1 + P2*v   (P0 == 1 -> a0 term vanishes)
        const float dp_a = fmaf(P1, b1, pv);

        // ---- input layer 2->32, directly in B-slot order ----
        float hv[16];
#pragma unroll
        for (int u = 0; u < 16; ++u)
            hv[u] = fmaxf(fmaf(wi0c[u], dp_a, fmaf(wi1c[u], dr, bic[u])), 0.0f);

        f16x8 B0 = __builtin_bit_cast(f16x8, (u32x4){
            packp(hv[0], hv[1]), packp(hv[2], hv[3]),
            packp(hv[4], hv[5]), packp(hv[6], hv[7])});
        f16x8 B1 = __builtin_bit_cast(f16x8, (u32x4){
            packp(hv[8], hv[9]), packp(hv[10], hv[11]),
            packp(hv[12], hv[13]), packp(hv[14], hv[15])});

        // ---- hidden layer A ----
        f32x16 acc = MFMA(AA0, B0, bAf);
        acc = MFMA(AA1, B1, acc);

        // relu(D) IS the next B (k-remap): B0 <- regs 0..7, B1 <- regs 8..15
        float v[16];
#pragma unroll
        for (int r = 0; r < 16; ++r)
            v[r] = fmaxf(acc[r], 0.0f);

        B0 = __builtin_bit_cast(f16x8, (u32x4){
            packp(v[0], v[1]), packp(v[2], v[3]),
            packp(v[4], v[5]), packp(v[6], v[7])});
        B1 = __builtin_bit_cast(f16x8, (u32x4){
            packp(v[8], v[9]), packp(v[10], v[11]),
            packp(v[12], v[13]), packp(v[14], v[15])});

        // ---- hidden layer B ----
        acc = MFMA(AB0, B0, bBf);
        acc = MFMA(AB1, B1, acc);

        // ---- output layer 32->1: per-lane partial dot over C/D rows ----
        float p0 = 0.f, p1 = 0.f, p2 = 0.f, p3 = 0.f;
#pragma unroll
        for (int r = 0; r < 16; r += 4) {
            p0 = fmaf(wo_r[r],     fmaxf(acc[r],     0.0f), p0);
            p1 = fmaf(wo_r[r + 1], fmaxf(acc[r + 1], 0.0f), p1);
            p2 = fmaf(wo_r[r + 2], fmaxf(acc[r + 2], 0.0f), p2);
            p3 = fmaf(wo_r[r + 3], fmaxf(acc[r + 3], 0.0f), p3);
        }
        float pd = (p0 + p1) + (p2 + p3);
        const float dp_b = pd + xr32(pd) + bo;   // symmetric: halves stay bit-identical

        const float sum = dp_a + dp_b;
        if (j >= 0) {                 // wave-uniform branch
            if (lane < 32 && t < T) out[t] = 0.5f * sum;
        }
        b1 = sum - b1;                // b1' = dp_b + (P1-1)*b1 + P2*v
        if (t < 0) b1 = 0.0f;         // warm-up clamp: exact b1=0 entering t=0

        P1 = nP1; pv = npv; dr = ndr;
    }
}

extern "C" void kernel_launch(void* const* d_in, const int* in_sizes, int n_in,
                              void* d_out, int out_size, void* d_ws, size_t ws_size,
                              hipStream_t stream) {
    const float* v_in  = (const float*)d_in[0];
    const float* vs_r  = (const float*)d_in[1];
    const float* fs    = (const float*)d_in[2];
    const float* W_in  = (const float*)d_in[3];
    const float* b_in  = (const float*)d_in[4];
    const float* W_h   = (const float*)d_in[5];
    const float* b_h   = (const float*)d_in[6];
    const float* W_out = (const float*)d_in[7];
    const float* b_out = (const float*)d_in[8];
    float* out = (float*)d_out;

    const int T = in_sizes[0];
    const int nChunks = (T + CHUNK - 1) / CHUNK;
    const int nWaves  = (nChunks + CPW - 1) / CPW;

    scan_kernel<<<nWaves, 64, 0, stream>>>(
        v_in, vs_r, fs, W_in, b_in, W_h, b_h, W_out, b_out, out, T);
}

// Round 12
// 96.317 us; speedup vs baseline: 1.8170x; 1.8170x over previous
//
#include <hip/hip_runtime.h>
#include <hip/hip_bf16.h>

#define C1_CONST 4.7e-9f
#define CHUNK 4       // output steps per chunk (3750 waves -> ~3.7 waves/SIMD)
#define WARM  12      // warm-up steps; |rho|~0.5 measured -> init err ~1e-4 << f16 floor
#define CPW   32      // chunks per wave (MFMA batch)

typedef _Float16 f16;
typedef unsigned int u32;
typedef f16   f16x8  __attribute__((ext_vector_type(8)));
typedef u32   u32x4  __attribute__((ext_vector_type(4)));
typedef float f32x16 __attribute__((ext_vector_type(16)));

#define MFMA(A, B, C) __builtin_amdgcn_mfma_f32_32x32x16_f16((A), (B), (C), 0, 0, 0)

// Pack two f32 -> packed f16 pair (single v_cvt_pkrtz).
__device__ __forceinline__ u32 packp(float x0, float x1) {
    return __builtin_bit_cast(u32, __builtin_amdgcn_cvt_pkrtz(x0, x1));
}

// Single kernel: 32 chunks per wave, hidden layers via v_mfma_f32_32x32x16_f16,
// pure f16 operands (validated r9/r10: absmax 1.95e-3 vs 1.375e-2 threshold).
// Per-step WDF port scalars computed INLINE (approx v_rcp, rel err ~1e-7).
//
// __launch_bounds__(64,2): (64,4) at r11 squeezed the arch-VGPR budget to 64
// -> 242 MB scratch spill traffic, 3x regression. (64,2) gives 76 VGPR,
// zero spill; the HW still co-schedules ~3-4 waves/SIMD at 76 VGPR since
// the 2nd arg is an allocator minimum, not a scheduler cap.
//
// LOGICAL-K REMAP (exact): k = (jj&3) + 4*h + 8*(jj>>2) + 16*s, so half h's
// B k-set equals the C/D rows it owns (row=(reg&3)+8*(reg>>2)+4*h) and
// D reg r = jj + 8*s: B0 = relu(D[0..7]), B1 = relu(D[8..15]) with zero
// cross-lane exchange between layers.
//
// Uses the P0 == 1 identity (g0 = g1+g2 exactly), so the a0 carry vanishes:
//   dp_a = P1*b1 + P2*v,  b1' = dp_a + dp_b - b1,  out = 0.5*(dp_a+dp_b)
__global__ __launch_bounds__(64, 2) void scan_kernel(
    const float* __restrict__ v_in, const float* __restrict__ vs_r,
    const float* __restrict__ fs,
    const float* __restrict__ W_in, const float* __restrict__ b_in,
    const float* __restrict__ W_h,  const float* __restrict__ b_h,
    const float* __restrict__ W_out, const float* __restrict__ b_out,
    float* __restrict__ out, int T) {
    const int lane = threadIdx.x & 63;
    const int c    = lane & 31;   // chunk slot / MFMA col / weight row m
    const int h    = lane >> 5;
    const int xaddr = (lane ^ 32) << 2;   // ds_bpermute addr for xor-32

    auto xr32 = [&](float v) {
        return __int_as_float(__builtin_amdgcn_ds_bpermute(xaddr, __float_as_int(v)));
    };

    // ---- MFMA A fragments (f16) for the two hidden layers ----
    f16x8 AA0, AA1, AB0, AB1;
#pragma unroll
    for (int jj = 0; jj < 8; ++jj) {
        int k0 = (jj & 3) + 4 * h + 8 * (jj >> 2);   // s=0
        int k1 = k0 + 16;                            // s=1
        AA0[jj] = (f16)W_h[c * 32 + k0];
        AA1[jj] = (f16)W_h[c * 32 + k1];
        AB0[jj] = (f16)W_h[1024 + c * 32 + k0];
        AB1[jj] = (f16)W_h[1024 + c * 32 + k1];
    }

    // ---- biases in C/D layout; W_out by C/D row ----
    f32x16 bAf, bBf;
    float wo_r[16];
#pragma unroll
    for (int r = 0; r < 16; ++r) {
        int row = (r & 3) + 8 * (r >> 2) + 4 * h;
        bAf[r] = b_h[row];
        bBf[r] = b_h[32 + row];
        wo_r[r] = W_out[row];
    }
    const float bo = b_out[0];

    // ---- input-layer constants, in B-slot order u = s*8 + jj ----
    float wi0c[16], wi1c[16], bic[16];
#pragma unroll
    for (int s = 0; s < 2; ++s)
#pragma unroll
        for (int jj = 0; jj < 8; ++jj) {
            int k = (jj & 3) + 4 * h + 8 * (jj >> 2) + 16 * s;
            wi0c[s * 8 + jj] = W_in[2 * k];
            wi1c[s * 8 + jj] = W_in[2 * k + 1];
            bic[s * 8 + jj]  = b_in[k];
        }

    const int cg = blockIdx.x * CPW + c;   // global chunk id
    const int ts = cg * CHUNK;             // first output step of this chunk

    // Inline per-step scalars: g1 = 2*C1*fs, g2 ~= 1/vs_r, inv ~= 1/(g1+g2);
    // P1 = g1*inv, pv = g2*inv*v, dr = inv/3000   (r0 = 1/(g1+g2) exactly).
    auto load_pre = [&](int tt, float& P1, float& pv, float& dr) {
        int tc = min(max(tt, 0), T - 1);
        float f  = fs[tc];
        float vr = vs_r[tc];
        float vv = v_in[tc];
        float g1 = (2.0f * C1_CONST) * f;
        float g2 = __builtin_amdgcn_rcpf(vr);
        float inv = __builtin_amdgcn_rcpf(g1 + g2);
        P1 = g1 * inv;
        pv = g2 * inv * vv;
        dr = inv * (1.0f / 3000.0f);
    };

    float b1 = 0.0f;
    float P1, pv, dr;
    load_pre(ts - WARM, P1, pv, dr);

    for (int j = -WARM; j < CHUNK; ++j) {
        const int t = ts + j;
        // prefetch next step's scalars (independent of this step's compute)
        float nP1, npv, ndr;
        load_pre(t + 1, nP1, npv, ndr);

        // dp_a = P1*b1 + P2*v   (P0 == 1 -> a0 term vanishes)
        const float dp_a = fmaf(P1, b1, pv);

        // ---- input layer 2->32, directly in B-slot order ----
        float hv[16];
#pragma unroll
        for (int u = 0; u < 16; ++u)
            hv[u] = fmaxf(fmaf(wi0c[u], dp_a, fmaf(wi1c[u], dr, bic[u])), 0.0f);

        f16x8 B0 = __builtin_bit_cast(f16x8, (u32x4){
            packp(hv[0], hv[1]), packp(hv[2], hv[3]),
            packp(hv[4], hv[5]), packp(hv[6], hv[7])});
        f16x8 B1 = __builtin_bit_cast(f16x8, (u32x4){
            packp(hv[8], hv[9]), packp(hv[10], hv[11]),
            packp(hv[12], hv[13]), packp(hv[14], hv[15])});

        // ---- hidden layer A ----
        f32x16 acc = MFMA(AA0, B0, bAf);
        acc = MFMA(AA1, B1, acc);

        // relu(D) IS the next B (k-remap): B0 <- regs 0..7, B1 <- regs 8..15
        float v[16];
#pragma unroll
        for (int r = 0; r < 16; ++r)
            v[r] = fmaxf(acc[r], 0.0f);

        B0 = __builtin_bit_cast(f16x8, (u32x4){
            packp(v[0], v[1]), packp(v[2], v[3]),
            packp(v[4], v[5]), packp(v[6], v[7])});
        B1 = __builtin_bit_cast(f16x8, (u32x4){
            packp(v[8], v[9]), packp(v[10], v[11]),
            packp(v[12], v[13]), packp(v[14], v[15])});

        // ---- hidden layer B ----
        acc = MFMA(AB0, B0, bBf);
        acc = MFMA(AB1, B1, acc);

        // ---- output layer 32->1: per-lane partial dot over C/D rows ----
        float p0 = 0.f, p1 = 0.f, p2 = 0.f, p3 = 0.f;
#pragma unroll
        for (int r = 0; r < 16; r += 4) {
            p0 = fmaf(wo_r[r],     fmaxf(acc[r],     0.0f), p0);
            p1 = fmaf(wo_r[r + 1], fmaxf(acc[r + 1], 0.0f), p1);
            p2 = fmaf(wo_r[r + 2], fmaxf(acc[r + 2], 0.0f), p2);
            p3 = fmaf(wo_r[r + 3], fmaxf(acc[r + 3], 0.0f), p3);
        }
        float pd = (p0 + p1) + (p2 + p3);
        const float dp_b = pd + xr32(pd) + bo;   // symmetric: halves stay bit-identical

        const float sum = dp_a + dp_b;
        if (j >= 0) {                 // wave-uniform branch
            if (lane < 32 && t < T) out[t] = 0.5f * sum;
        }
        b1 = sum - b1;                // b1' = dp_b + (P1-1)*b1 + P2*v
        if (t < 0) b1 = 0.0f;         // warm-up clamp: exact b1=0 entering t=0

        P1 = nP1; pv = npv; dr = ndr;
    }
}

extern "C" void kernel_launch(void* const* d_in, const int* in_sizes, int n_in,
                              void* d_out, int out_size, void* d_ws, size_t ws_size,
                              hipStream_t stream) {
    const float* v_in  = (const float*)d_in[0];
    const float* vs_r  = (const float*)d_in[1];
    const float* fs    = (const float*)d_in[2];
    const float* W_in  = (const float*)d_in[3];
    const float* b_in  = (const float*)d_in[4];
    const float* W_h   = (const float*)d_in[5];
    const float* b_h   = (const float*)d_in[6];
    const float* W_out = (const float*)d_in[7];
    const float* b_out = (const float*)d_in[8];
    float* out = (float*)d_out;

    const int T = in_sizes[0];
    const int nChunks = (T + CHUNK - 1) / CHUNK;
    const int nWaves  = (nChunks + CPW - 1) / CPW;

    scan_kernel<<<nWaves, 64, 0, stream>>>(
        v_in, vs_r, fs, W_in, b_in, W_h, b_h, W_out, b_out, out, T);
}

// Round 13
// 88.956 us; speedup vs baseline: 1.9673x; 1.0827x over previous
//
#include <hip/hip_runtime.h>
#include <hip/hip_bf16.h>

#define C1_CONST 4.7e-9f
#define CHUNK 5       // output steps per chunk (3000 waves -> ~2.9 waves/SIMD)
#define WARM  10      // warm-up steps; |rho|~0.5 measured -> init err ~5e-4 < f16 floor
#define CPW   32      // chunks per wave (MFMA batch)

typedef _Float16 f16;
typedef unsigned int u32;
typedef f16   f16x8  __attribute__((ext_vector_type(8)));
typedef u32   u32x4  __attribute__((ext_vector_type(4)));
typedef float f32x16 __attribute__((ext_vector_type(16)));

#define MFMA(A, B, C) __builtin_amdgcn_mfma_f32_32x32x16_f16((A), (B), (C), 0, 0, 0)

// Pack two f32 -> packed f16 pair (single v_cvt_pkrtz).
__device__ __forceinline__ u32 packp(float x0, float x1) {
    return __builtin_bit_cast(u32, __builtin_amdgcn_cvt_pkrtz(x0, x1));
}

// Single kernel: 32 chunks per wave, hidden layers via v_mfma_f32_32x32x16_f16,
// pure f16 operands (validated r9-r12: absmax 1.95e-3 vs 1.375e-2 threshold).
// Per-step WDF port scalars computed INLINE (approx v_rcp, rel err ~1e-7).
//
// __launch_bounds__(64,2): (64,4) at r11 squeezed the arch-VGPR budget to 64
// -> 242 MB scratch spill traffic, 3x regression. (64,2) gives 76 VGPR,
// zero spill; HW co-schedules ~3 waves/SIMD at 76 VGPR (2nd arg is an
// allocator minimum, not a scheduler cap).
//
// LOGICAL-K REMAP (exact): k = (jj&3) + 4*h + 8*(jj>>2) + 16*s, so half h's
// B k-set equals the C/D rows it owns (row=(reg&3)+8*(reg>>2)+4*h) and
// D reg r = jj + 8*s: B0 = relu(D[0..7]), B1 = relu(D[8..15]) with zero
// cross-lane exchange between layers.
//
// Uses the P0 == 1 identity (g0 = g1+g2 exactly), so the a0 carry vanishes:
//   dp_a = P1*b1 + P2*v,  b1' = dp_a + dp_b - b1,  out = 0.5*(dp_a+dp_b)
__global__ __launch_bounds__(64, 2) void scan_kernel(
    const float* __restrict__ v_in, const float* __restrict__ vs_r,
    const float* __restrict__ fs,
    const float* __restrict__ W_in, const float* __restrict__ b_in,
    const float* __restrict__ W_h,  const float* __restrict__ b_h,
    const float* __restrict__ W_out, const float* __restrict__ b_out,
    float* __restrict__ out, int T) {
    const int lane = threadIdx.x & 63;
    const int c    = lane & 31;   // chunk slot / MFMA col / weight row m
    const int h    = lane >> 5;
    const int xaddr = (lane ^ 32) << 2;   // ds_bpermute addr for xor-32

    auto xr32 = [&](float v) {
        return __int_as_float(__builtin_amdgcn_ds_bpermute(xaddr, __float_as_int(v)));
    };

    // ---- MFMA A fragments (f16) for the two hidden layers ----
    f16x8 AA0, AA1, AB0, AB1;
#pragma unroll
    for (int jj = 0; jj < 8; ++jj) {
        int k0 = (jj & 3) + 4 * h + 8 * (jj >> 2);   // s=0
        int k1 = k0 + 16;                            // s=1
        AA0[jj] = (f16)W_h[c * 32 + k0];
        AA1[jj] = (f16)W_h[c * 32 + k1];
        AB0[jj] = (f16)W_h[1024 + c * 32 + k0];
        AB1[jj] = (f16)W_h[1024 + c * 32 + k1];
    }

    // ---- biases in C/D layout; W_out by C/D row ----
    f32x16 bAf, bBf;
    float wo_r[16];
#pragma unroll
    for (int r = 0; r < 16; ++r) {
        int row = (r & 3) + 8 * (r >> 2) + 4 * h;
        bAf[r] = b_h[row];
        bBf[r] = b_h[32 + row];
        wo_r[r] = W_out[row];
    }
    const float bo = b_out[0];

    // ---- input-layer constants, in B-slot order u = s*8 + jj ----
    float wi0c[16], wi1c[16], bic[16];
#pragma unroll
    for (int s = 0; s < 2; ++s)
#pragma unroll
        for (int jj = 0; jj < 8; ++jj) {
            int k = (jj & 3) + 4 * h + 8 * (jj >> 2) + 16 * s;
            wi0c[s * 8 + jj] = W_in[2 * k];
            wi1c[s * 8 + jj] = W_in[2 * k + 1];
            bic[s * 8 + jj]  = b_in[k];
        }

    const int cg = blockIdx.x * CPW + c;   // global chunk id
    const int ts = cg * CHUNK;             // first output step of this chunk

    // Inline per-step scalars: g1 = 2*C1*fs, g2 ~= 1/vs_r, inv ~= 1/(g1+g2);
    // P1 = g1*inv, pv = g2*inv*v, dr = inv/3000   (r0 = 1/(g1+g2) exactly).
    auto load_pre = [&](int tt, float& P1, float& pv, float& dr) {
        int tc = min(max(tt, 0), T - 1);
        float f  = fs[tc];
        float vr = vs_r[tc];
        float vv = v_in[tc];
        float g1 = (2.0f * C1_CONST) * f;
        float g2 = __builtin_amdgcn_rcpf(vr);
        float inv = __builtin_amdgcn_rcpf(g1 + g2);
        P1 = g1 * inv;
        pv = g2 * inv * vv;
        dr = inv * (1.0f / 3000.0f);
    };

    float b1 = 0.0f;
    float P1, pv, dr;
    load_pre(ts - WARM, P1, pv, dr);

    for (int j = -WARM; j < CHUNK; ++j) {
        const int t = ts + j;
        // prefetch next step's scalars (independent of this step's compute)
        float nP1, npv, ndr;
        load_pre(t + 1, nP1, npv, ndr);

        // dp_a = P1*b1 + P2*v   (P0 == 1 -> a0 term vanishes)
        const float dp_a = fmaf(P1, b1, pv);

        // ---- input layer 2->32, directly in B-slot order ----
        float hv[16];
#pragma unroll
        for (int u = 0; u < 16; ++u)
            hv[u] = fmaxf(fmaf(wi0c[u], dp_a, fmaf(wi1c[u], dr, bic[u])), 0.0f);

        f16x8 B0 = __builtin_bit_cast(f16x8, (u32x4){
            packp(hv[0], hv[1]), packp(hv[2], hv[3]),
            packp(hv[4], hv[5]), packp(hv[6], hv[7])});
        f16x8 B1 = __builtin_bit_cast(f16x8, (u32x4){
            packp(hv[8], hv[9]), packp(hv[10], hv[11]),
            packp(hv[12], hv[13]), packp(hv[14], hv[15])});

        // ---- hidden layer A ----
        f32x16 acc = MFMA(AA0, B0, bAf);
        acc = MFMA(AA1, B1, acc);

        // relu(D) IS the next B (k-remap): B0 <- regs 0..7, B1 <- regs 8..15
        float v[16];
#pragma unroll
        for (int r = 0; r < 16; ++r)
            v[r] = fmaxf(acc[r], 0.0f);

        B0 = __builtin_bit_cast(f16x8, (u32x4){
            packp(v[0], v[1]), packp(v[2], v[3]),
            packp(v[4], v[5]), packp(v[6], v[7])});
        B1 = __builtin_bit_cast(f16x8, (u32x4){
            packp(v[8], v[9]), packp(v[10], v[11]),
            packp(v[12], v[13]), packp(v[14], v[15])});

        // ---- hidden layer B ----
        acc = MFMA(AB0, B0, bBf);
        acc = MFMA(AB1, B1, acc);

        // ---- output layer 32->1: per-lane partial dot over C/D rows ----
        float p0 = 0.f, p1 = 0.f, p2 = 0.f, p3 = 0.f;
#pragma unroll
        for (int r = 0; r < 16; r += 4) {
            p0 = fmaf(wo_r[r],     fmaxf(acc[r],     0.0f), p0);
            p1 = fmaf(wo_r[r + 1], fmaxf(acc[r + 1], 0.0f), p1);
            p2 = fmaf(wo_r[r + 2], fmaxf(acc[r + 2], 0.0f), p2);
            p3 = fmaf(wo_r[r + 3], fmaxf(acc[r + 3], 0.0f), p3);
        }
        float pd = (p0 + p1) + (p2 + p3);
        const float dp_b = pd + xr32(pd) + bo;   // symmetric: halves stay bit-identical

        const float sum = dp_a + dp_b;
        if (j >= 0) {                 // wave-uniform branch
            if (lane < 32 && t < T) out[t] = 0.5f * sum;
        }
        b1 = sum - b1;                // b1' = dp_b + (P1-1)*b1 + P2*v
        if (t < 0) b1 = 0.0f;         // warm-up clamp: exact b1=0 entering t=0

        P1 = nP1; pv = npv; dr = ndr;
    }
}

extern "C" void kernel_launch(void* const* d_in, const int* in_sizes, int n_in,
                              void* d_out, int out_size, void* d_ws, size_t ws_size,
                              hipStream_t stream) {
    const float* v_in  = (const float*)d_in[0];
    const float* vs_r  = (const float*)d_in[1];
    const float* fs    = (const float*)d_in[2];
    const float* W_in  = (const float*)d_in[3];
    const float* b_in  = (const float*)d_in[4];
    const float* W_h   = (const float*)d_in[5];
    const float* b_h   = (const float*)d_in[6];
    const float* W_out = (const float*)d_in[7];
    const float* b_out = (const float*)d_in[8];
    float* out = (float*)d_out;

    const int T = in_sizes[0];
    const int nChunks = (T + CHUNK - 1) / CHUNK;
    const int nWaves  = (nChunks + CPW - 1) / CPW;

    scan_kernel<<<nWaves, 64, 0, stream>>>(
        v_in, vs_r, fs, W_in, b_in, W_h, b_h, W_out, b_out, out, T);
}